// Round 1
// baseline (443.858 us; speedup 1.0000x reference)
//
#include <hip/hip_runtime.h>

#define T_STEPS 128
#define CIN     16
#define HH      64
#define WW      64
#define COUT    64
#define HWSZ    (HH * WW)          // 4096
#define CHW     (COUT * HWSZ)      // 262144  (out per-t stride)
#define XCHW    (CIN * HWSZ)       // 65536   (x per-t stride)

// pass-1 tiling
#define TCH       2                 // timesteps per block
#define TILE_H    4
#define TILE_W    16
#define HALO_H    6
#define HALO_W    18
#define LDS_STR   20                // padded row stride (floats), 80B = 16B aligned
#define CI_CHUNK  8
#define STAGE_N   (TCH * CI_CHUNK * HALO_H * HALO_W)   // 1728

__global__ __launch_bounds__(256, 2)
void spiking_conv_pass1(const float* __restrict__ x, const float* __restrict__ Wt,
                        const float* __restrict__ b, float* __restrict__ out) {
    __shared__ float xs[TCH * CI_CHUNK * HALO_H * LDS_STR];  // 1920 floats = 7.5 KB

    const int tid = threadIdx.x;
    const int bx  = blockIdx.x;            // 64 spatial tiles: 16 rows x 4 cols
    const int th  = bx >> 2;
    const int tw  = bx & 3;
    const int h0  = th * TILE_H;
    const int w0  = tw * TILE_W;
    const int t0  = blockIdx.y * TCH;      // 64 t-chunks
    const int co  = blockIdx.z * 32 + (tid >> 3);  // 2 co-groups of 32
    const int s   = tid & 7;               // 8 spatial threads per co
    const int ph  = (s >> 2) * 2;          // 0,2
    const int pw  = (s & 3) * 4;           // 0,4,8,12

    float acc[TCH][8];
#pragma unroll
    for (int t = 0; t < TCH; ++t)
#pragma unroll
        for (int i = 0; i < 8; ++i) acc[t][i] = 0.f;

    for (int cc = 0; cc < 2; ++cc) {
        // ---- weights for (co, ci-chunk): 72 floats, hoisted to VGPRs ----
        float w[72];
        {
            const float4* wp = (const float4*)(Wt + co * (CIN * 9) + cc * 72);
#pragma unroll
            for (int i = 0; i < 18; ++i) {
                float4 v = wp[i];
                w[4 * i + 0] = v.x; w[4 * i + 1] = v.y;
                w[4 * i + 2] = v.z; w[4 * i + 3] = v.w;
            }
        }

        // ---- stage x tile (+halo, zero-padded) into LDS ----
        const int cibase = cc * CI_CHUNK;
        for (int e = tid; e < STAGE_N; e += 256) {
            int t  = e / (CI_CHUNK * HALO_H * HALO_W);           // /864
            int r1 = e - t * (CI_CHUNK * HALO_H * HALO_W);
            int ci = r1 / (HALO_H * HALO_W);                     // /108
            int r2 = r1 - ci * (HALO_H * HALO_W);
            int r  = r2 / HALO_W;                                // /18
            int c  = r2 - r * HALO_W;
            int gh = h0 - 1 + r;
            int gw = w0 - 1 + c;
            float v = 0.f;
            if ((unsigned)gh < HH && (unsigned)gw < WW)
                v = x[(t0 + t) * XCHW + (cibase + ci) * HWSZ + gh * WW + gw];
            xs[((t * CI_CHUNK + ci) * HALO_H + r) * LDS_STR + c] = v;
        }
        __syncthreads();

        // ---- compute ----
#pragma unroll
        for (int t = 0; t < TCH; ++t) {
#pragma unroll
            for (int ci = 0; ci < CI_CHUNK; ++ci) {
                float xp[4][6];
#pragma unroll
                for (int r = 0; r < 4; ++r) {
                    const float* row =
                        &xs[((t * CI_CHUNK + ci) * HALO_H + ph + r) * LDS_STR + pw];
                    float4 v4 = *(const float4*)row;       // ds_read_b128
                    float2 v2 = *(const float2*)(row + 4); // ds_read_b64
                    xp[r][0] = v4.x; xp[r][1] = v4.y; xp[r][2] = v4.z; xp[r][3] = v4.w;
                    xp[r][4] = v2.x; xp[r][5] = v2.y;
                }
#pragma unroll
                for (int ky = 0; ky < 3; ++ky)
#pragma unroll
                    for (int kx = 0; kx < 3; ++kx) {
                        float wv = w[ci * 9 + ky * 3 + kx];
#pragma unroll
                        for (int pr = 0; pr < 2; ++pr)
#pragma unroll
                            for (int pc = 0; pc < 4; ++pc)
                                acc[t][pr * 4 + pc] += wv * xp[pr + ky][pc + kx];
                    }
            }
        }
        __syncthreads();  // before restage
    }

    // ---- epilogue: + bias, float4 stores (64B contiguous per 4 lanes) ----
    const float bias = b[co];
#pragma unroll
    for (int t = 0; t < TCH; ++t)
#pragma unroll
        for (int pr = 0; pr < 2; ++pr) {
            float4 o;
            o.x = acc[t][pr * 4 + 0] + bias;
            o.y = acc[t][pr * 4 + 1] + bias;
            o.z = acc[t][pr * 4 + 2] + bias;
            o.w = acc[t][pr * 4 + 3] + bias;
            *(float4*)(out + (t0 + t) * CHW + co * HWSZ +
                       (h0 + ph + pr) * WW + (w0 + pw)) = o;
        }
}

// In-place sequential spiking scan over T. Each thread owns one (co,h,w).
__global__ __launch_bounds__(256)
void spiking_scan_pass2(float* __restrict__ io) {
    const int idx = blockIdx.x * 256 + threadIdx.x;  // 0..262143
    float* p = io + idx;
    float state = 0.f;
#pragma unroll 4
    for (int t = 0; t < T_STEPS; ++t) {
        float v = p[t * CHW];
        state += v;
        const bool spike = (state >= 8.0f);
        p[t * CHW] = spike ? 1.0f : 0.0f;
        state = spike ? 0.0f : state;            // reset-to-value (0)
        state = (state > -1.0f) ? state : -1.0f; // Threshold(-1,-1)
    }
}

extern "C" void kernel_launch(void* const* d_in, const int* in_sizes, int n_in,
                              void* d_out, int out_size, void* d_ws, size_t ws_size,
                              hipStream_t stream) {
    const float* x = (const float*)d_in[0];   // [128,16,64,64]
    const float* W = (const float*)d_in[1];   // [64,16,3,3]
    const float* b = (const float*)d_in[2];   // [64]
    float* out = (float*)d_out;               // [128,64,64,64]

    dim3 g1(64, 64, 2);   // 64 spatial tiles x 64 t-chunks x 2 co-groups
    spiking_conv_pass1<<<g1, 256, 0, stream>>>(x, W, b, out);

    spiking_scan_pass2<<<CHW / 256, 256, 0, stream>>>(out);
}

// Round 2
// 326.264 us; speedup vs baseline: 1.3604x; 1.3604x over previous
//
#include <hip/hip_runtime.h>

#define T_STEPS 128
#define CIN     16
#define HH      64
#define WW      64
#define COUT    64
#define HWSZ    (HH * WW)          // 4096
#define CHW     (COUT * HWSZ)      // 262144
#define XCHW    (CIN * HWSZ)       // 65536

// pass-1 tiling: one t, one 32x32 spatial tile per block; all 16 ci in LDS.
#define TILE    32
#define HALO    34
#define LSTR    36                  // padded LDS row stride (floats)
#define PLANE   (HALO * LSTR)       // 1224 floats per ci
#define NSTAGE  (CIN * HALO * HALO) // 18496 elements staged per block

__global__ __launch_bounds__(256, 2)
void spiking_conv_pass1(const float* __restrict__ x, const float* __restrict__ Wt,
                        const float* __restrict__ b, float* __restrict__ out) {
    __shared__ float xs[CIN * PLANE];   // 19584 floats = 76.5 KB

    const int tid = threadIdx.x;
    const int t   = blockIdx.y;
    const int h0  = (blockIdx.x >> 1) * TILE;
    const int w0  = (blockIdx.x & 1) * TILE;

    // ---- stage the full 16-ci tile (+halo, zero-padded) once ----
    const float* xt = x + t * XCHW;
    for (int e = tid; e < NSTAGE; e += 256) {
        int ci  = e / (HALO * HALO);            // /1156 (magic mul)
        int rem = e - ci * (HALO * HALO);
        int r   = rem / HALO;                   // /34
        int c   = rem - r * HALO;
        int gh  = h0 - 1 + r;
        int gw  = w0 - 1 + c;
        float v = 0.f;
        if ((unsigned)gh < HH && (unsigned)gw < WW)
            v = xt[ci * HWSZ + gh * WW + gw];
        xs[ci * PLANE + r * LSTR + c] = v;
    }
    __syncthreads();

    // ---- compute: thread = 2x2 patch, loop co-groups of 8 ----
    const int tr  = tid >> 4;        // 0..15
    const int tc  = tid & 15;        // 0..15
    const int pr0 = tr * 2;
    const int pc0 = tc * 2;
    float* outt = out + t * CHW;

#pragma unroll 1
    for (int cog = 0; cog < 8; ++cog) {
        float acc[8][2][2];
#pragma unroll
        for (int j = 0; j < 8; ++j)
#pragma unroll
            for (int pr = 0; pr < 2; ++pr)
#pragma unroll
                for (int pc = 0; pc < 2; ++pc) acc[j][pr][pc] = 0.f;

#pragma unroll 2
        for (int ci = 0; ci < CIN; ++ci) {
            // x patch 4x4 into registers (8x ds_read_b64, conflict-free)
            float xv[4][4];
#pragma unroll
            for (int dr = 0; dr < 4; ++dr) {
                const float* row = &xs[ci * PLANE + (pr0 + dr) * LSTR + pc0];
                float2 a = *(const float2*)row;
                float2 c2 = *(const float2*)(row + 2);
                xv[dr][0] = a.x; xv[dr][1] = a.y;
                xv[dr][2] = c2.x; xv[dr][3] = c2.y;
            }
            // weights: indices are wave-uniform -> s_load, SGPR operands
#pragma unroll
            for (int j = 0; j < 8; ++j) {
                const float* wr = Wt + (cog * 8 + j) * (CIN * 9) + ci * 9;
#pragma unroll
                for (int ky = 0; ky < 3; ++ky)
#pragma unroll
                    for (int kx = 0; kx < 3; ++kx) {
                        const float wv = wr[ky * 3 + kx];
                        acc[j][0][0] += wv * xv[ky    ][kx    ];
                        acc[j][0][1] += wv * xv[ky    ][kx + 1];
                        acc[j][1][0] += wv * xv[ky + 1][kx    ];
                        acc[j][1][1] += wv * xv[ky + 1][kx + 1];
                    }
            }
        }

        // ---- epilogue: +bias, float2 stores (16 lanes x 8B contiguous) ----
#pragma unroll
        for (int j = 0; j < 8; ++j) {
            const float bias = b[cog * 8 + j];
#pragma unroll
            for (int pr = 0; pr < 2; ++pr) {
                float2 o;
                o.x = acc[j][pr][0] + bias;
                o.y = acc[j][pr][1] + bias;
                *(float2*)&outt[(cog * 8 + j) * HWSZ +
                                (h0 + pr0 + pr) * WW + (w0 + pc0)] = o;
            }
        }
    }
}

// In-place sequential spiking scan over T; float4 columns for MLP.
__global__ __launch_bounds__(256)
void spiking_scan_pass2(float* __restrict__ io) {
    const int idx = blockIdx.x * 256 + threadIdx.x;   // 0..65535
    float4* p = (float4*)io + idx;                    // column stride CHW/4
    float sx = 0.f, sy = 0.f, sz = 0.f, sw = 0.f;
#pragma unroll 8
    for (int t = 0; t < T_STEPS; ++t) {
        float4 v = p[(size_t)t * (CHW / 4)];
        float ox, oy, oz, ow;
        sx += v.x; ox = (sx >= 8.0f) ? 1.f : 0.f; sx = (sx >= 8.0f) ? 0.f : sx; sx = fmaxf(sx, -1.0f);
        sy += v.y; oy = (sy >= 8.0f) ? 1.f : 0.f; sy = (sy >= 8.0f) ? 0.f : sy; sy = fmaxf(sy, -1.0f);
        sz += v.z; oz = (sz >= 8.0f) ? 1.f : 0.f; sz = (sz >= 8.0f) ? 0.f : sz; sz = fmaxf(sz, -1.0f);
        sw += v.w; ow = (sw >= 8.0f) ? 1.f : 0.f; sw = (sw >= 8.0f) ? 0.f : sw; sw = fmaxf(sw, -1.0f);
        p[(size_t)t * (CHW / 4)] = make_float4(ox, oy, oz, ow);
    }
}

extern "C" void kernel_launch(void* const* d_in, const int* in_sizes, int n_in,
                              void* d_out, int out_size, void* d_ws, size_t ws_size,
                              hipStream_t stream) {
    const float* x = (const float*)d_in[0];   // [128,16,64,64]
    const float* W = (const float*)d_in[1];   // [64,16,3,3]
    const float* b = (const float*)d_in[2];   // [64]
    float* out = (float*)d_out;               // [128,64,64,64]

    dim3 g1(4, 128);   // 4 spatial tiles x 128 timesteps (512 blocks, 2/CU)
    spiking_conv_pass1<<<g1, 256, 0, stream>>>(x, W, b, out);

    spiking_scan_pass2<<<(CHW / 4) / 256, 256, 0, stream>>>(out);
}

// Round 3
// 292.708 us; speedup vs baseline: 1.5164x; 1.1146x over previous
//
#include <hip/hip_runtime.h>

#define T_STEPS 128
#define CIN     16
#define HH      64
#define WW      64
#define COUT    64
#define HWSZ    (HH * WW)          // 4096
#define CHW     (COUT * HWSZ)      // 262144
#define XCHW    (CIN * HWSZ)       // 65536

// pass-1: one t, one 32x32 spatial tile per 512-thread block; all 16 ci in LDS.
#define TILE    32
#define HALO    34
#define LSTR    36                  // padded LDS row stride (floats)
#define PLANE   (HALO * LSTR)       // 1224 floats per ci
#define NSTAGE  (CIN * HALO * HALO) // 18496 elements staged per block

__global__ __launch_bounds__(512, 4)
void spiking_conv_pass1(const float* __restrict__ x, const float* __restrict__ Wt,
                        const float* __restrict__ b, float* __restrict__ out) {
    __shared__ float xs[CIN * PLANE];   // 78336 B -> 2 blocks/CU, 16 waves/CU

    const int tid = threadIdx.x;        // 0..511
    const int t   = blockIdx.y;
    const int h0  = (blockIdx.x >> 1) * TILE;
    const int w0  = (blockIdx.x & 1) * TILE;

    // ---- stage the full 16-ci tile (+halo, zero-padded) once ----
    const float* xt = x + t * XCHW;
    for (int e = tid; e < NSTAGE; e += 512) {
        int ci  = e / (HALO * HALO);
        int rem = e - ci * (HALO * HALO);
        int r   = rem / HALO;
        int c   = rem - r * HALO;
        int gh  = h0 - 1 + r;
        int gw  = w0 - 1 + c;
        float v = 0.f;
        if ((unsigned)gh < HH && (unsigned)gw < WW)
            v = xt[ci * HWSZ + gh * WW + gw];
        xs[ci * PLANE + r * LSTR + c] = v;
    }
    __syncthreads();

    // ---- compute: thread = 1x2 patch (row pr0, cols pc0..pc0+1) ----
    const int pr0 = tid >> 4;          // 0..31
    const int pc0 = (tid & 15) * 2;    // 0..30
    float* outt = out + t * CHW;

#pragma unroll 1
    for (int cog = 0; cog < 8; ++cog) {
        float acc[8][2];
#pragma unroll
        for (int j = 0; j < 8; ++j) { acc[j][0] = 0.f; acc[j][1] = 0.f; }

#pragma unroll 1
        for (int ci = 0; ci < CIN; ++ci) {
            // weights FIRST (s_load, long latency): full 72-float block
            float w[72];
#pragma unroll
            for (int j = 0; j < 8; ++j)
#pragma unroll
                for (int k = 0; k < 9; ++k)
                    w[j * 9 + k] = Wt[(cog * 8 + j) * (CIN * 9) + ci * 9 + k];

            // x patch 3x4 (6x ds_read_b64)
            float xv[3][4];
#pragma unroll
            for (int dr = 0; dr < 3; ++dr) {
                const float* row = &xs[ci * PLANE + (pr0 + dr) * LSTR + pc0];
                float2 a = *(const float2*)row;
                float2 c2 = *(const float2*)(row + 2);
                xv[dr][0] = a.x; xv[dr][1] = a.y;
                xv[dr][2] = c2.x; xv[dr][3] = c2.y;
            }

#pragma unroll
            for (int j = 0; j < 8; ++j)
#pragma unroll
                for (int ky = 0; ky < 3; ++ky)
#pragma unroll
                    for (int kx = 0; kx < 3; ++kx) {
                        const float wv = w[j * 9 + ky * 3 + kx];
                        acc[j][0] += wv * xv[ky][kx];
                        acc[j][1] += wv * xv[ky][kx + 1];
                    }
        }

        // ---- epilogue: +bias, float2 stores ----
#pragma unroll
        for (int j = 0; j < 8; ++j) {
            const float bias = b[cog * 8 + j];
            float2 o;
            o.x = acc[j][0] + bias;
            o.y = acc[j][1] + bias;
            *(float2*)&outt[(cog * 8 + j) * HWSZ + (h0 + pr0) * WW + (w0 + pc0)] = o;
        }
    }
}

// In-place sequential spiking scan; scalar columns, batch-8 loads in flight.
__global__ __launch_bounds__(256)
void spiking_scan_pass2(float* __restrict__ io) {
    const int idx = blockIdx.x * 256 + threadIdx.x;   // 0..262143
    float* p = io + idx;
    float s = 0.f;
#pragma unroll 1
    for (int tb = 0; tb < T_STEPS / 8; ++tb) {
        float v[8];
#pragma unroll
        for (int i = 0; i < 8; ++i) v[i] = p[(tb * 8 + i) * CHW];
#pragma unroll
        for (int i = 0; i < 8; ++i) {
            s += v[i];
            const bool sp = (s >= 8.0f);
            v[i] = sp ? 1.0f : 0.0f;
            s = sp ? 0.0f : s;              // reset-to-value (0)
            s = fmaxf(s, -1.0f);            // Threshold(-1,-1)
        }
#pragma unroll
        for (int i = 0; i < 8; ++i) p[(tb * 8 + i) * CHW] = v[i];
    }
}

extern "C" void kernel_launch(void* const* d_in, const int* in_sizes, int n_in,
                              void* d_out, int out_size, void* d_ws, size_t ws_size,
                              hipStream_t stream) {
    const float* x = (const float*)d_in[0];   // [128,16,64,64]
    const float* W = (const float*)d_in[1];   // [64,16,3,3]
    const float* b = (const float*)d_in[2];   // [64]
    float* out = (float*)d_out;               // [128,64,64,64]

    dim3 g1(4, 128);   // 4 spatial tiles x 128 timesteps = 512 blocks (2/CU)
    spiking_conv_pass1<<<g1, 512, 0, stream>>>(x, W, b, out);

    spiking_scan_pass2<<<CHW / 256, 256, 0, stream>>>(out);
}